// Round 9
// baseline (29.025 us; speedup 1.0000x reference)
//
#include <hip/hip_runtime.h>
#include <math.h>

#define N_PTS   16384
#define EPS     1e-7f
#define JSPLIT  8
#define JSLICE  (N_PTS / JSPLIT)   // 2048
#define NBLK    256                // == grid size (tail-block detection)
#define NTHR    1024
#define NWAVE   (NTHR / 64)        // 16
#define MAXACT  2048               // >= nact (binomial mean ~1638, 10 sigma margin)
#define PPW     8                  // points per wave group

// Persistent device scratch. g_partial slots read by the tail are all written
// earlier in the SAME launch (exactly once per (side,slice,pos)); g_done is
// zero on load and reset to zero at the end of every launch.
__device__ unsigned g_partial[2 * JSPLIT * MAXACT];   // [(side*8+s)*MAXACT + pos]
__device__ int      g_done = 0;

// One kernel. Block = (side, j-slice, group-subset). Each block self-serves:
//  P1: block-local compaction of ti==1 (full scan, deterministic)
//  P2: transform q-slice -> LDS; transform its PPW-groups' p-points (pose is
//      fixed = poses[1] since active points have ti==1)
//  P3: min over the LDS q-slice, pw folded out of the inner loop
//  P4: exactly-once plain store of per-(point,slice) partial mins
//  P5: last block to finish combines slices, recomputes l2/count, writes out
__global__ __launch_bounds__(NTHR) void fused_kernel(
        const float* __restrict__ pts, const int* __restrict__ ti,
        const float* __restrict__ est_poses, const float* __restrict__ gt_poses,
        float* __restrict__ out) {
    const int t    = threadIdx.x;
    const int lane = t & 63;
    const int w    = t >> 6;                  // wave id in block, 0..15
    const int side = blockIdx.x >> 7;         // 0: P=gt,Q=est ; 1: P=est,Q=gt
    const int s    = (blockIdx.x >> 4) & 7;   // j-slice
    const int bsub = blockIdx.x & 15;         // group subset

    __shared__ int    s_cnt[256];
    __shared__ int    s_glist[MAXACT];
    __shared__ float4 s_q[JSLICE];            // 32 KB
    __shared__ float  s_red[NTHR];
    __shared__ int    s_nact;
    __shared__ int    s_lastflag;

    // ---- P1: block-local compaction (deterministic order) ----
    int vals[16];
    #pragma unroll
    for (int i = 0; i < 16; ++i)
        vals[i] = ti[(w * 16 + i) * 64 + lane];
    #pragma unroll
    for (int i = 0; i < 16; ++i) {
        unsigned long long mask = __ballot(vals[i] == 1);
        if (lane == 0) s_cnt[w * 16 + i] = __popcll(mask);
    }
    __syncthreads();
    int ocnt = (t < 256) ? s_cnt[t] : 0;
    for (int d = 1; d < 256; d <<= 1) {       // Hillis-Steele inclusive scan
        int v = (t < 256 && t >= d) ? s_cnt[t - d] : 0;
        __syncthreads();
        if (t < 256) s_cnt[t] += v;
        __syncthreads();
    }
    if (t == 255) s_nact = s_cnt[255];
    if (t < 256) s_cnt[t] -= ocnt;            // exclusive offset per chunk
    __syncthreads();
    const int nact = min(s_nact, MAXACT);
    #pragma unroll
    for (int i = 0; i < 16; ++i) {
        int c = w * 16 + i;
        unsigned long long mask = __ballot(vals[i] == 1);
        if (vals[i] == 1) {
            int rank = __popcll(mask & ((1ull << lane) - 1ull));
            int pos  = s_cnt[c] + rank;
            if (pos < MAXACT) s_glist[pos] = c * 64 + lane;
        }
    }

    // ---- P2a: stage transformed q-slice into LDS ----
    const float* qposes = side ? gt_poses : est_poses;
    for (int r = t; r < JSLICE; r += NTHR) {  // 2 rounds
        int j = s * JSLICE + r;
        float px = pts[3 * j], py = pts[3 * j + 1], pz = pts[3 * j + 2];
        const float* M = qposes + ti[j] * 16;
        float x = M[0] * px + M[1] * py + M[2]  * pz + M[3];
        float y = M[4] * px + M[5] * py + M[6]  * pz + M[7];
        float z = M[8] * px + M[9] * py + M[10] * pz + M[11];
        s_q[r] = make_float4(x, y, z, x * x + y * y + z * z);
    }
    __syncthreads();

    // ---- P2b + P3 + P4: per-wave group of PPW active points ----
    const int g     = bsub * NWAVE + w;       // 0..255 covers all groups
    const int gbase = g * PPW;
    if (gbase < nact) {
        // active points all have ti==1 -> fixed pose row
        const float* PM = (side ? est_poses : gt_poses) + 16;
        float p2x[PPW], p2y[PPW], p2z[PPW], pw[PPW], m[PPW];
        #pragma unroll
        for (int k = 0; k < PPW; ++k) {
            int pos = gbase + k;
            if (pos >= nact) pos = nact - 1;  // clamp: dup, store skipped
            int idx = s_glist[pos];
            float px = pts[3 * idx], py = pts[3 * idx + 1], pz = pts[3 * idx + 2];
            float x = PM[0] * px + PM[1] * py + PM[2]  * pz + PM[3];
            float y = PM[4] * px + PM[5] * py + PM[6]  * pz + PM[7];
            float z = PM[8] * px + PM[9] * py + PM[10] * pz + PM[11];
            p2x[k] = -2.0f * x; p2y[k] = -2.0f * y; p2z[k] = -2.0f * z;
            pw[k]  = x * x + y * y + z * z;
            m[k]   = 3.4e38f;
        }
        for (int jj = 0; jj < JSLICE; jj += 128) {   // 16 iterations
            float4 q0 = s_q[jj + lane];
            float4 q1 = s_q[jj + 64 + lane];
            #pragma unroll
            for (int k = 0; k < PPW; ++k) {
                // e = |q|^2 - 2 p.q  (pw folded out; min3-fusable)
                float e0 = fmaf(p2x[k], q0.x,
                           fmaf(p2y[k], q0.y, fmaf(p2z[k], q0.z, q0.w)));
                float e1 = fmaf(p2x[k], q1.x,
                           fmaf(p2y[k], q1.y, fmaf(p2z[k], q1.z, q1.w)));
                m[k] = fminf(m[k], fminf(e0, e1));
            }
        }
        #pragma unroll
        for (int k = 0; k < PPW; ++k) {
            #pragma unroll
            for (int o = 32; o > 0; o >>= 1)
                m[k] = fminf(m[k], __shfl_xor(m[k], o));
        }
        if (lane == 0) {
            #pragma unroll
            for (int k = 0; k < PPW; ++k) {
                int pos = gbase + k;
                if (pos < nact)
                    g_partial[(side * JSPLIT + s) * MAXACT + pos] =
                        __float_as_uint(pw[k] + m[k]);
            }
        }
    }

    // ---- tail-block detection ----
    __syncthreads();
    if (t == 0) {
        __threadfence();                      // release plain partial stores
        s_lastflag = (atomicAdd(&g_done, 1) == NBLK - 1);
    }
    __syncthreads();
    if (!s_lastflag) return;

    // ---- P5: finalize in the last block ----
    float msum = 0.0f;
    for (int a = t; a < 2 * nact; a += NTHR) {
        int aside = a >= nact;
        int pos   = aside ? a - nact : a;
        unsigned base = (unsigned)(aside * JSPLIT) * MAXACT + pos;
        float mn = 3.4e38f;
        #pragma unroll
        for (int ss = 0; ss < JSPLIT; ++ss) {
            // identity-atomic read: coherent vs other XCDs' plain stores
            unsigned u = atomicAdd(&g_partial[base + ss * MAXACT], 0u);
            mn = fminf(mn, __uint_as_float(u));
        }
        msum += mn;
    }
    // l2 from own LDS list (fixed pose row 1 for both)
    float l2s = 0.0f;
    const float* PE1 = est_poses + 16;
    const float* PG1 = gt_poses + 16;
    for (int a = t; a < nact; a += NTHR) {
        int idx = s_glist[a];
        float px = pts[3 * idx], py = pts[3 * idx + 1], pz = pts[3 * idx + 2];
        float ex = PE1[0] * px + PE1[1] * py + PE1[2]  * pz + PE1[3];
        float ey = PE1[4] * px + PE1[5] * py + PE1[6]  * pz + PE1[7];
        float ez = PE1[8] * px + PE1[9] * py + PE1[10] * pz + PE1[11];
        float gx = PG1[0] * px + PG1[1] * py + PG1[2]  * pz + PG1[3];
        float gy = PG1[4] * px + PG1[5] * py + PG1[6]  * pz + PG1[7];
        float gz = PG1[8] * px + PG1[9] * py + PG1[10] * pz + PG1[11];
        float dx = ex - gx, dy = ey - gy, dz = ez - gz;
        l2s += sqrtf(dx * dx + dy * dy + dz * dz);
    }
    s_red[t] = msum;
    __syncthreads();
    for (int d = NTHR / 2; d > 0; d >>= 1) {
        if (t < d) s_red[t] += s_red[t + d];
        __syncthreads();
    }
    float chamfer_raw = s_red[0];
    __syncthreads();
    s_red[t] = l2s;
    __syncthreads();
    for (int d = NTHR / 2; d > 0; d >>= 1) {
        if (t < d) s_red[t] += s_red[t + d];
        __syncthreads();
    }
    if (t == 0) {
        float inv = 1.0f / ((float)nact + EPS);
        out[0] = 0.5f * chamfer_raw * inv;
        out[1] = s_red[0] * inv;
        g_done = 0;                           // clean state for next replay
    }
}

extern "C" void kernel_launch(void* const* d_in, const int* in_sizes, int n_in,
                              void* d_out, int out_size, void* d_ws, size_t ws_size,
                              hipStream_t stream) {
    const float* pts       = (const float*)d_in[0];
    const int*   ti        = (const int*)d_in[1];
    const float* est_poses = (const float*)d_in[2];
    const float* gt_poses  = (const float*)d_in[3];
    float* out = (float*)d_out;

    fused_kernel<<<NBLK, NTHR, 0, stream>>>(pts, ti, est_poses, gt_poses, out);
}

// Round 10
// 28.557 us; speedup vs baseline: 1.0164x; 1.0164x over previous
//
#include <hip/hip_runtime.h>
#include <math.h>

#define N_PTS   16384
#define EPS     1e-7f
#define JSPLIT  8
#define JSLICE  (N_PTS / JSPLIT)   // 2048
#define NBLK    256                // == grid size (tail-block detection)
#define NTHR    1024
#define NWAVE   (NTHR / 64)        // 16
#define MAXACT  2048               // >= nact (binomial mean ~1638, 10 sigma margin)
#define PPW     8                  // points per wave group

// Persistent device scratch. g_partial slots read by the tail are all written
// earlier in the SAME launch (exactly once per (side,slice,pos)); g_done is
// zero on load and reset to zero at the end of every launch.
__device__ unsigned g_partial[2 * JSPLIT * MAXACT];   // [(side*8+s)*MAXACT + pos]
__device__ int      g_done = 0;

// One kernel. Block = (side, j-slice, group-subset). Each block self-serves:
//  P1: block-local compaction of ti==1 (full scan, deterministic)
//  P2: transform q-slice -> LDS; transform its PPW-groups' p-points (pose is
//      fixed = poses[1] since active points have ti==1)
//  P3: min over the LDS q-slice, pw folded out of the inner loop
//  P4: exactly-once plain store of per-(point,slice) partial mins
//  P5: last block to finish combines slices, recomputes l2/count, writes out
__global__ __launch_bounds__(NTHR) void fused_kernel(
        const float* __restrict__ pts, const int* __restrict__ ti,
        const float* __restrict__ est_poses, const float* __restrict__ gt_poses,
        float* __restrict__ out) {
    const int t    = threadIdx.x;
    const int lane = t & 63;
    const int w    = t >> 6;                  // wave id in block, 0..15
    const int side = blockIdx.x >> 7;         // 0: P=gt,Q=est ; 1: P=est,Q=gt
    const int s    = (blockIdx.x >> 4) & 7;   // j-slice
    const int bsub = blockIdx.x & 15;         // group subset

    __shared__ int    s_cnt[256];
    __shared__ int    s_glist[MAXACT];
    __shared__ float4 s_q[JSLICE];            // 32 KB
    __shared__ float  s_red[NTHR];
    __shared__ int    s_nact;
    __shared__ int    s_lastflag;

    // ---- P1: block-local compaction (deterministic order) ----
    int vals[16];
    #pragma unroll
    for (int i = 0; i < 16; ++i)
        vals[i] = ti[(w * 16 + i) * 64 + lane];
    #pragma unroll
    for (int i = 0; i < 16; ++i) {
        unsigned long long mask = __ballot(vals[i] == 1);
        if (lane == 0) s_cnt[w * 16 + i] = __popcll(mask);
    }
    __syncthreads();
    int ocnt = (t < 256) ? s_cnt[t] : 0;
    for (int d = 1; d < 256; d <<= 1) {       // Hillis-Steele inclusive scan
        int v = (t < 256 && t >= d) ? s_cnt[t - d] : 0;
        __syncthreads();
        if (t < 256) s_cnt[t] += v;
        __syncthreads();
    }
    if (t == 255) s_nact = s_cnt[255];
    if (t < 256) s_cnt[t] -= ocnt;            // exclusive offset per chunk
    __syncthreads();
    const int nact = min(s_nact, MAXACT);
    #pragma unroll
    for (int i = 0; i < 16; ++i) {
        int c = w * 16 + i;
        unsigned long long mask = __ballot(vals[i] == 1);
        if (vals[i] == 1) {
            int rank = __popcll(mask & ((1ull << lane) - 1ull));
            int pos  = s_cnt[c] + rank;
            if (pos < MAXACT) s_glist[pos] = c * 64 + lane;
        }
    }

    // ---- P2a: stage transformed q-slice into LDS ----
    const float* qposes = side ? gt_poses : est_poses;
    for (int r = t; r < JSLICE; r += NTHR) {  // 2 rounds
        int j = s * JSLICE + r;
        float px = pts[3 * j], py = pts[3 * j + 1], pz = pts[3 * j + 2];
        const float* M = qposes + ti[j] * 16;
        float x = M[0] * px + M[1] * py + M[2]  * pz + M[3];
        float y = M[4] * px + M[5] * py + M[6]  * pz + M[7];
        float z = M[8] * px + M[9] * py + M[10] * pz + M[11];
        s_q[r] = make_float4(x, y, z, x * x + y * y + z * z);
    }
    __syncthreads();

    // ---- P2b + P3 + P4: per-wave group of PPW active points ----
    const int g     = bsub * NWAVE + w;       // 0..255 covers all groups
    const int gbase = g * PPW;
    if (gbase < nact) {
        // active points all have ti==1 -> fixed pose row
        const float* PM = (side ? est_poses : gt_poses) + 16;
        float p2x[PPW], p2y[PPW], p2z[PPW], pw[PPW], m[PPW];
        #pragma unroll
        for (int k = 0; k < PPW; ++k) {
            int pos = gbase + k;
            if (pos >= nact) pos = nact - 1;  // clamp: dup, store skipped
            int idx = s_glist[pos];
            float px = pts[3 * idx], py = pts[3 * idx + 1], pz = pts[3 * idx + 2];
            float x = PM[0] * px + PM[1] * py + PM[2]  * pz + PM[3];
            float y = PM[4] * px + PM[5] * py + PM[6]  * pz + PM[7];
            float z = PM[8] * px + PM[9] * py + PM[10] * pz + PM[11];
            p2x[k] = -2.0f * x; p2y[k] = -2.0f * y; p2z[k] = -2.0f * z;
            pw[k]  = x * x + y * y + z * z;
            m[k]   = 3.4e38f;
        }
        for (int jj = 0; jj < JSLICE; jj += 128) {   // 16 iterations
            float4 q0 = s_q[jj + lane];
            float4 q1 = s_q[jj + 64 + lane];
            #pragma unroll
            for (int k = 0; k < PPW; ++k) {
                // e = |q|^2 - 2 p.q  (pw folded out; min3-fusable)
                float e0 = fmaf(p2x[k], q0.x,
                           fmaf(p2y[k], q0.y, fmaf(p2z[k], q0.z, q0.w)));
                float e1 = fmaf(p2x[k], q1.x,
                           fmaf(p2y[k], q1.y, fmaf(p2z[k], q1.z, q1.w)));
                m[k] = fminf(m[k], fminf(e0, e1));
            }
        }
        #pragma unroll
        for (int k = 0; k < PPW; ++k) {
            #pragma unroll
            for (int o = 32; o > 0; o >>= 1)
                m[k] = fminf(m[k], __shfl_xor(m[k], o));
        }
        if (lane == 0) {
            #pragma unroll
            for (int k = 0; k < PPW; ++k) {
                int pos = gbase + k;
                if (pos < nact)
                    g_partial[(side * JSPLIT + s) * MAXACT + pos] =
                        __float_as_uint(pw[k] + m[k]);
            }
        }
    }

    // ---- tail-block detection ----
    __syncthreads();
    if (t == 0) {
        __threadfence();                      // release plain partial stores
        s_lastflag = (atomicAdd(&g_done, 1) == NBLK - 1);
    }
    __syncthreads();
    if (!s_lastflag) return;

    // ---- P5: finalize in the last block ----
    float msum = 0.0f;
    for (int a = t; a < 2 * nact; a += NTHR) {
        int aside = a >= nact;
        int pos   = aside ? a - nact : a;
        unsigned base = (unsigned)(aside * JSPLIT) * MAXACT + pos;
        float mn = 3.4e38f;
        #pragma unroll
        for (int ss = 0; ss < JSPLIT; ++ss) {
            // identity-atomic read: coherent vs other XCDs' plain stores
            unsigned u = atomicAdd(&g_partial[base + ss * MAXACT], 0u);
            mn = fminf(mn, __uint_as_float(u));
        }
        msum += mn;
    }
    // l2 from own LDS list (fixed pose row 1 for both)
    float l2s = 0.0f;
    const float* PE1 = est_poses + 16;
    const float* PG1 = gt_poses + 16;
    for (int a = t; a < nact; a += NTHR) {
        int idx = s_glist[a];
        float px = pts[3 * idx], py = pts[3 * idx + 1], pz = pts[3 * idx + 2];
        float ex = PE1[0] * px + PE1[1] * py + PE1[2]  * pz + PE1[3];
        float ey = PE1[4] * px + PE1[5] * py + PE1[6]  * pz + PE1[7];
        float ez = PE1[8] * px + PE1[9] * py + PE1[10] * pz + PE1[11];
        float gx = PG1[0] * px + PG1[1] * py + PG1[2]  * pz + PG1[3];
        float gy = PG1[4] * px + PG1[5] * py + PG1[6]  * pz + PG1[7];
        float gz = PG1[8] * px + PG1[9] * py + PG1[10] * pz + PG1[11];
        float dx = ex - gx, dy = ey - gy, dz = ez - gz;
        l2s += sqrtf(dx * dx + dy * dy + dz * dz);
    }
    s_red[t] = msum;
    __syncthreads();
    for (int d = NTHR / 2; d > 0; d >>= 1) {
        if (t < d) s_red[t] += s_red[t + d];
        __syncthreads();
    }
    float chamfer_raw = s_red[0];
    __syncthreads();
    s_red[t] = l2s;
    __syncthreads();
    for (int d = NTHR / 2; d > 0; d >>= 1) {
        if (t < d) s_red[t] += s_red[t + d];
        __syncthreads();
    }
    if (t == 0) {
        float inv = 1.0f / ((float)nact + EPS);
        out[0] = 0.5f * chamfer_raw * inv;
        out[1] = s_red[0] * inv;
        g_done = 0;                           // clean state for next replay
    }
}

extern "C" void kernel_launch(void* const* d_in, const int* in_sizes, int n_in,
                              void* d_out, int out_size, void* d_ws, size_t ws_size,
                              hipStream_t stream) {
    const float* pts       = (const float*)d_in[0];
    const int*   ti        = (const int*)d_in[1];
    const float* est_poses = (const float*)d_in[2];
    const float* gt_poses  = (const float*)d_in[3];
    float* out = (float*)d_out;

    fused_kernel<<<NBLK, NTHR, 0, stream>>>(pts, ti, est_poses, gt_poses, out);
}

// Round 11
// 26.405 us; speedup vs baseline: 1.0992x; 1.0815x over previous
//
#include <hip/hip_runtime.h>
#include <math.h>

#define N_PTS   16384
#define EPS     1e-7f
#define JSPLIT  8
#define JSLICE  (N_PTS / JSPLIT)   // 2048
#define NBLK    256                // == grid size (tail-block detection)
#define NTHR    1024
#define NWAVE   (NTHR / 64)        // 16
#define MAXACT  2048               // >= nact (binomial mean ~1638)
#define PPW     8                  // points per wave group (4 v2f pairs)

typedef float v2f __attribute__((ext_vector_type(2)));

// Persistent device scratch. Invariant at entry of EVERY call (first call via
// .bss zero-init, later calls via the tail block's atomic resets):
// g_minkey[*] == 0 (the inverted-key sentinel = +infinity), g_done == 0.
__device__ unsigned g_minkey[2 * MAXACT];   // [side*MAXACT + pos]
__device__ int      g_done = 0;

// inverted monotonic key: min over floats == max over keys; 0 == "infinity"
// (no finite float maps to 0), so .bss zero IS the sentinel.
__device__ inline unsigned ikey(float f) {
    unsigned b = __float_as_uint(f);
    unsigned fk = (b & 0x80000000u) ? ~b : (b | 0x80000000u);
    return ~fk;
}
__device__ inline float idec(unsigned k) {
    unsigned fk = ~k;
    unsigned b = (fk & 0x80000000u) ? (fk ^ 0x80000000u) : ~fk;
    return __uint_as_float(b);
}

// One kernel. Block = (side, j-slice, group-subset).
//  P1: block-local compaction of ti==1 (ballot + single-wave shfl scan)
//  P2: transform q-slice -> LDS (AoS float4); transform own p-points (pose is
//      fixed = poses[1] since active points have ti==1), packed into v2f pairs
//  P3: packed min over the LDS q-slice (pk_fma + min3), pw folded out
//  P4: per-point atomicMax of inverted key (pw + min)
//  P5: last block to finish: atomicExch-read+reset keys, recompute l2, output
__global__ __launch_bounds__(NTHR) void fused_kernel(
        const float* __restrict__ pts, const int* __restrict__ ti,
        const float* __restrict__ est_poses, const float* __restrict__ gt_poses,
        float* __restrict__ out) {
    const int t    = threadIdx.x;
    const int lane = t & 63;
    const int w    = t >> 6;                  // wave id in block, 0..15
    const int side = blockIdx.x >> 7;         // 0: P=gt,Q=est ; 1: P=est,Q=gt
    const int s    = (blockIdx.x >> 4) & 7;   // j-slice
    const int bsub = blockIdx.x & 15;         // group subset

    __shared__ int    s_cnt[256];
    __shared__ int    s_glist[MAXACT];
    __shared__ float4 s_q[JSLICE];            // 32 KB
    __shared__ float  s_red[NTHR];
    __shared__ int    s_nact;
    __shared__ int    s_lastflag;

    // ---- P1: block-local compaction (deterministic order) ----
    int vals[16];
    #pragma unroll
    for (int i = 0; i < 16; ++i)
        vals[i] = ti[(w * 16 + i) * 64 + lane];
    #pragma unroll
    for (int i = 0; i < 16; ++i) {
        unsigned long long mask = __ballot(vals[i] == 1);
        if (lane == 0) s_cnt[w * 16 + i] = __popcll(mask);
    }
    __syncthreads();
    if (w == 0) {                             // single-wave exclusive scan
        int c[4];
        #pragma unroll
        for (int i = 0; i < 4; ++i) c[i] = s_cnt[lane * 4 + i];
        int tot = c[0] + c[1] + c[2] + c[3];
        int x = tot;
        #pragma unroll
        for (int o = 1; o < 64; o <<= 1) {
            int y = __shfl_up(x, o);
            if (lane >= o) x += y;
        }
        int excl = x - tot;
        s_cnt[lane * 4 + 0] = excl;
        s_cnt[lane * 4 + 1] = excl + c[0];
        s_cnt[lane * 4 + 2] = excl + c[0] + c[1];
        s_cnt[lane * 4 + 3] = excl + c[0] + c[1] + c[2];
        if (lane == 63) s_nact = x;
    }
    __syncthreads();
    const int nact = min(s_nact, MAXACT);
    #pragma unroll
    for (int i = 0; i < 16; ++i) {
        int c = w * 16 + i;
        unsigned long long mask = __ballot(vals[i] == 1);
        if (vals[i] == 1) {
            int rank = __popcll(mask & ((1ull << lane) - 1ull));
            int pos  = s_cnt[c] + rank;
            if (pos < MAXACT) s_glist[pos] = c * 64 + lane;
        }
    }

    // ---- P2a: stage transformed q-slice into LDS ----
    const float* qposes = side ? gt_poses : est_poses;
    for (int r = t; r < JSLICE; r += NTHR) {  // 2 rounds
        int j = s * JSLICE + r;
        float px = pts[3 * j], py = pts[3 * j + 1], pz = pts[3 * j + 2];
        const float* M = qposes + ti[j] * 16;
        float x = M[0] * px + M[1] * py + M[2]  * pz + M[3];
        float y = M[4] * px + M[5] * py + M[6]  * pz + M[7];
        float z = M[8] * px + M[9] * py + M[10] * pz + M[11];
        s_q[r] = make_float4(x, y, z, x * x + y * y + z * z);
    }
    __syncthreads();                          // covers s_glist + s_q

    // ---- P2b + P3 + P4: per-wave group of PPW points, packed pairs ----
    const int g     = bsub * NWAVE + w;       // 0..255 covers all groups
    const int gbase = g * PPW;
    if (gbase < nact) {
        const float* PM = (side ? est_poses : gt_poses) + 16;  // pose row 1
        v2f p2x[4], p2y[4], p2z[4], pw2[4], macc[4];
        #pragma unroll
        for (int kp = 0; kp < 4; ++kp) {
            float xx[2], yy[2], zz[2], ww[2];
            #pragma unroll
            for (int h = 0; h < 2; ++h) {
                int pos = gbase + 2 * kp + h;
                if (pos >= nact) pos = nact - 1;   // clamp: dup, store skipped
                int idx = s_glist[pos];
                float px = pts[3 * idx], py = pts[3 * idx + 1], pz = pts[3 * idx + 2];
                float x = PM[0] * px + PM[1] * py + PM[2]  * pz + PM[3];
                float y = PM[4] * px + PM[5] * py + PM[6]  * pz + PM[7];
                float z = PM[8] * px + PM[9] * py + PM[10] * pz + PM[11];
                xx[h] = x; yy[h] = y; zz[h] = z;
                ww[h] = x * x + y * y + z * z;
            }
            p2x[kp] = (v2f){-2.0f * xx[0], -2.0f * xx[1]};
            p2y[kp] = (v2f){-2.0f * yy[0], -2.0f * yy[1]};
            p2z[kp] = (v2f){-2.0f * zz[0], -2.0f * zz[1]};
            pw2[kp] = (v2f){ww[0], ww[1]};
            macc[kp] = (v2f){3.4e38f, 3.4e38f};
        }

        for (int jj = 0; jj < JSLICE; jj += 128) {   // 16 iterations
            float4 q0 = s_q[jj + lane];
            float4 q1 = s_q[jj + 64 + lane];
            #pragma unroll
            for (int kp = 0; kp < 4; ++kp) {
                // e = |q|^2 - 2 p.q ; identical fma chain per half (pk_fma)
                v2f e0 = p2x[kp] * q0.x + (p2y[kp] * q0.y + (p2z[kp] * q0.z + q0.w));
                v2f e1 = p2x[kp] * q1.x + (p2y[kp] * q1.y + (p2z[kp] * q1.z + q1.w));
                macc[kp].x = fminf(macc[kp].x, fminf(e0.x, e1.x));  // v_min3
                macc[kp].y = fminf(macc[kp].y, fminf(e0.y, e1.y));
            }
        }

        float mm[PPW];
        #pragma unroll
        for (int kp = 0; kp < 4; ++kp) {
            mm[2 * kp]     = macc[kp].x;
            mm[2 * kp + 1] = macc[kp].y;
        }
        #pragma unroll
        for (int k = 0; k < PPW; ++k) {
            #pragma unroll
            for (int o = 32; o > 0; o >>= 1)
                mm[k] = fminf(mm[k], __shfl_xor(mm[k], o));
        }
        if (lane == 0) {
            #pragma unroll
            for (int kp = 0; kp < 4; ++kp) {
                int pos0 = gbase + 2 * kp;
                if (pos0 < nact)
                    atomicMax(&g_minkey[side * MAXACT + pos0],
                              ikey(pw2[kp].x + mm[2 * kp]));
                if (pos0 + 1 < nact)
                    atomicMax(&g_minkey[side * MAXACT + pos0 + 1],
                              ikey(pw2[kp].y + mm[2 * kp + 1]));
            }
        }
    }

    // ---- tail-block detection ----
    __syncthreads();
    if (t == 0) {
        __threadfence();                      // order vs our atomicMaxes
        s_lastflag = (atomicAdd(&g_done, 1) == NBLK - 1);
    }
    __syncthreads();
    if (!s_lastflag) return;

    // ---- P5: finalize in the last block ----
    float msum = 0.0f;
    for (int a = t; a < 2 * nact; a += NTHR) {
        int aside = a >= nact;
        int pos   = a - aside * nact;
        // atomic read+reset: coherent vs other XCDs; restores sentinel 0
        unsigned k = atomicExch(&g_minkey[aside * MAXACT + pos], 0u);
        msum += idec(k);                      // every active key was written
    }
    // l2 from own LDS list (fixed pose row 1 for both)
    float l2s = 0.0f;
    const float* PE1 = est_poses + 16;
    const float* PG1 = gt_poses + 16;
    for (int a = t; a < nact; a += NTHR) {
        int idx = s_glist[a];
        float px = pts[3 * idx], py = pts[3 * idx + 1], pz = pts[3 * idx + 2];
        float ex = PE1[0] * px + PE1[1] * py + PE1[2]  * pz + PE1[3];
        float ey = PE1[4] * px + PE1[5] * py + PE1[6]  * pz + PE1[7];
        float ez = PE1[8] * px + PE1[9] * py + PE1[10] * pz + PE1[11];
        float gx = PG1[0] * px + PG1[1] * py + PG1[2]  * pz + PG1[3];
        float gy = PG1[4] * px + PG1[5] * py + PG1[6]  * pz + PG1[7];
        float gz = PG1[8] * px + PG1[9] * py + PG1[10] * pz + PG1[11];
        float dx = ex - gx, dy = ey - gy, dz = ez - gz;
        l2s += sqrtf(dx * dx + dy * dy + dz * dz);
    }
    s_red[t] = msum;
    __syncthreads();
    for (int d = NTHR / 2; d > 0; d >>= 1) {
        if (t < d) s_red[t] += s_red[t + d];
        __syncthreads();
    }
    float chamfer_raw = s_red[0];
    __syncthreads();
    s_red[t] = l2s;
    __syncthreads();
    for (int d = NTHR / 2; d > 0; d >>= 1) {
        if (t < d) s_red[t] += s_red[t + d];
        __syncthreads();
    }
    if (t == 0) {
        float inv = 1.0f / ((float)nact + EPS);
        out[0] = 0.5f * chamfer_raw * inv;
        out[1] = s_red[0] * inv;
        atomicExch(&g_done, 0);               // clean state for next replay
    }
}

extern "C" void kernel_launch(void* const* d_in, const int* in_sizes, int n_in,
                              void* d_out, int out_size, void* d_ws, size_t ws_size,
                              hipStream_t stream) {
    const float* pts       = (const float*)d_in[0];
    const int*   ti        = (const int*)d_in[1];
    const float* est_poses = (const float*)d_in[2];
    const float* gt_poses  = (const float*)d_in[3];
    float* out = (float*)d_out;

    fused_kernel<<<NBLK, NTHR, 0, stream>>>(pts, ti, est_poses, gt_poses, out);
}